// Round 10
// baseline (128.466 us; speedup 1.0000x reference)
//
#include <hip/hip_runtime.h>

// NCA update, fused bf16-MFMA, high-occupancy version (no W1 in LDS).
//   out = W2 @ relu(Conv3x3(state; W1fold) + b1) + b2
// W1fold folds sobel_x/sobel_y/identity into one 16->128 3x3 conv (K=144,
// b1 at col 144 of stride-152 rows; B supplies bf16 1.0 at k=144).
//
// KEY CHANGE vs R4/R8: A-fragments (W1fold) are read straight from global
// ws1 every use. All 1024 blocks read the same 40KB -> L1/L2 resident.
// LDS holds ONLY the double-buffered swizzled bf16 state tile (25.3KB)
// -> occupancy cap moves from LDS (2 blocks/CU) to VGPR (~4 blocks/CU).
// launch_bounds(256,2): the only proven spill-free regalloc regime
// (R7: (256,3) spilled; R9: (512,4) gave a 64-VGPR cap and 281MB scratch).
// Block: 4 waves, region 16 rows x 64 cols, 4 tiles of 4 rows; one
// __syncthreads per tile (double buffer). Grid 1024 = 4 blocks/CU, no tail.

constexpr int Hc = 1024, Wc = 1024;
constexpr int W1S = 152;       // shorts per W1fold row: 144 weights + b1 + 7 pad
constexpr int W1PAD = 19968;   // shorts: 128*152=19456, padded to 39*1024 B
constexpr int TBUF = 6 * 66 * 16;  // shorts per tile buffer (12672 B)

typedef __attribute__((ext_vector_type(8))) short short8;
typedef __attribute__((ext_vector_type(4))) float f32x4;
typedef __attribute__((ext_vector_type(2))) unsigned int uint2v;

__device__ __forceinline__ unsigned short bfu(float x) {
    __bf16 b = (__bf16)x;                       // RNE
    return __builtin_bit_cast(unsigned short, b);
}
__device__ __forceinline__ unsigned pack2(float a, float b) {
    return (unsigned)bfu(a) | ((unsigned)bfu(b) << 16);
}

__device__ __forceinline__ void swap32(unsigned x, unsigned y, unsigned& o0, unsigned& o1) {
#if __has_builtin(__builtin_amdgcn_permlane32_swap)
    uint2v r = __builtin_amdgcn_permlane32_swap(x, y, false, false);
    o0 = r[0]; o1 = r[1];
#else
    unsigned xs = (unsigned)__shfl_xor((int)x, 32, 64);
    unsigned ys = (unsigned)__shfl_xor((int)y, 32, 64);
    const bool hi = (threadIdx.x & 32) != 0;
    o0 = hi ? ys : x;
    o1 = hi ? y : xs;
#endif
}
__device__ __forceinline__ void swap16(unsigned a, unsigned b, unsigned& o0, unsigned& o1) {
#if __has_builtin(__builtin_amdgcn_permlane16_swap)
    uint2v r = __builtin_amdgcn_permlane16_swap(a, b, false, false);
    o0 = r[0]; o1 = r[1];
#else
    unsigned as = (unsigned)__shfl_xor((int)a, 16, 64);
    unsigned bs = (unsigned)__shfl_xor((int)b, 16, 64);
    const bool hi = (threadIdx.x & 16) != 0;
    o0 = hi ? bs : a;
    o1 = hi ? b : as;
#endif
}

// ---------------- prep: W1fold (+b1) and W2 -> bf16 in ws ----------------
__global__ __launch_bounds__(256) void nca_prep(
    const float* __restrict__ W1c, const float* __restrict__ b1c,
    const float* __restrict__ W2c,
    unsigned short* __restrict__ ws1, unsigned short* __restrict__ ws2)
{
    const int u = blockIdx.x * 256 + threadIdx.x;
    if (u < W1PAD) {
        const int row = u / W1S, k = u - row * W1S;
        float v = 0.f;
        if (row < 128) {
            if (k < 144) {
                const int pos = k >> 4, c = k & 15;
                const int dy = pos / 3, dx = pos - dy * 3;
                v = (float)((dx - 1) * (1 + (dy == 1))) * W1c[row * 48 + c]
                  + (float)((dy - 1) * (1 + (dx == 1))) * W1c[row * 48 + 16 + c];
                if (pos == 4) v += W1c[row * 48 + 32 + c];
            } else if (k == 144) {
                v = b1c[row];
            }
        }
        ws1[u] = bfu(v);
    } else if (u < W1PAD + 16 * 128) {
        const int w = u - W1PAD;
        ws2[w] = bfu(W2c[w]);
    }
}

// ---------------- main ----------------
template <bool USE_WS>
__global__ __launch_bounds__(256, 2) void nca_main(
    const float* __restrict__ state,
    const float* __restrict__ W1c, const float* __restrict__ b1c,
    const float* __restrict__ W2c, const float* __restrict__ b2c,
    const unsigned short* __restrict__ ws1,   // W1fold bf16 [128][152] (+pad)
    const unsigned short* __restrict__ ws2,   // W2 bf16 [16][128]
    float* __restrict__ out)
{
    __shared__ short tile[2][TBUF];           // 2 x 12672 B, XOR-swizzled
    __shared__ short w1f[USE_WS ? 16 : W1PAD];  // fallback only

    const int tid  = threadIdx.x;
    const int lane = tid & 63;
    const int wv   = tid >> 6;
    const int p    = lane & 15;
    const int g    = lane >> 4;

    const int bid = (int)blockIdx.x;          // natural: XCD column striping
    const int r0 = (bid >> 4) << 4;           // 64 rowgroups x 16 rows
    const int c0 = (bid & 15) << 6;           // 16 colgroups x 64 cols

    if constexpr (!USE_WS) {
        for (int u = tid; u < W1PAD; u += 256) {
            const int row = u / W1S, k = u - row * W1S;
            float v = 0.f;
            if (row < 128) {
                if (k < 144) {
                    const int pos = k >> 4, c = k & 15;
                    const int dy = pos / 3, dx = pos - dy * 3;
                    v = (float)((dx - 1) * (1 + (dy == 1))) * W1c[row * 48 + c]
                      + (float)((dy - 1) * (1 + (dx == 1))) * W1c[row * 48 + 16 + c];
                    if (pos == 4) v += W1c[row * 48 + 32 + c];
                } else if (k == 144) {
                    v = b1c[row];
                }
            }
            w1f[u] = (short)bfu(v);
        }
    }

    // ---- staging constants: 792 16B-chunks = 3*256 + 24 (slot 3, tid<24) ----
    // chunk j: pixel pidx=j>>1 (row tr=pidx/66, col tc=pidx%66), half hb=j&1.
    // LDS byte (within buffer) = j*16 ^ ((j&8)<<1).
    int grow[4], gcol[4], lofs[4];
    #pragma unroll
    for (int s = 0; s < 4; ++s) {
        const int j = tid + 256 * s;
        const int jj = (j < 792) ? j : 791;
        const int pidx = jj >> 1, hb = jj & 1;
        const int tr = pidx / 66, tc = pidx - tr * 66;
        grow[s] = tr;
        gcol[s] = (((c0 - 1 + tc) & (Wc - 1)) << 6) + (hb << 5);   // bytes
        lofs[s] = (jj * 16) ^ ((jj & 8) << 1);                      // bytes
    }
    const bool has3 = (tid < 24);

    // ---- W2 fragments + b2 (registers) ----
    short8 w2f[4];
    if (USE_WS) {
        const unsigned short* wsp = ws2 + p * 128 + 8 * g;
        #pragma unroll
        for (int kc = 0; kc < 4; ++kc)
            w2f[kc] = *reinterpret_cast<const short8*>(wsp + 32 * kc);
    } else {
        #pragma unroll
        for (int kc = 0; kc < 4; ++kc) {
            const float* qp = W2c + p * 128 + 32 * kc + 8 * g;
            const float4 A = *reinterpret_cast<const float4*>(qp);
            const float4 B = *reinterpret_cast<const float4*>(qp + 4);
            uint4 uu{pack2(A.x, A.y), pack2(A.z, A.w), pack2(B.x, B.y), pack2(B.z, B.w)};
            w2f[kc] = __builtin_bit_cast(short8, uu);
        }
    }
    const float4 bv = *reinterpret_cast<const float4*>(b2c + 4 * g);

    // ---- per-lane im2col B addresses (within-buffer, constant across t) ----
    // chunk i<4: pos = 2i + (g>>1), ch-half gb = g&1. i=4: pos 8 (g<2);
    // g==2 -> bf16 1.0 at k=144 (b1 fold); g==3 -> zeros.
    const int gb = g & 1;
    int baddr[5];
    #pragma unroll
    for (int i = 0; i < 5; ++i) {
        const int pos = (i < 4) ? (2 * i + (g >> 1)) : 8;
        const int dy = pos / 3, dx = pos - 3 * dy;
        const int pidx = (wv + dy) * 66 + (p + dx);
        baddr[i] = (pidx * 32 + gb * 16) ^ ((pidx & 4) << 2);      // bytes
    }
    const int abase = p * W1S + 8 * g;        // short index into W1fold

    int ocol[4];
    #pragma unroll
    for (int pt = 0; pt < 4; ++pt) ocol[pt] = ((c0 + 16 * pt + p) << 6) + (g << 4);

    const char* stby = (const char*)state;
    char* outby = (char*)out;

    // ---- prologue: stage buf0 (input rows r0-1 .. r0+4) ----
    {
        float4 sa[4], sb[4];
        #pragma unroll
        for (int s = 0; s < 4; ++s) {
            if (s < 3 || has3) {
                const long sr = (long)((r0 - 1 + grow[s]) & (Hc - 1));
                const char* bp = stby + (sr << 16) + gcol[s];
                sa[s] = *reinterpret_cast<const float4*>(bp);
                sb[s] = *reinterpret_cast<const float4*>(bp + 16);
            }
        }
        #pragma unroll
        for (int s = 0; s < 4; ++s) {
            if (s < 3 || has3) {
                uint4 uu{pack2(sa[s].x, sa[s].y), pack2(sa[s].z, sa[s].w),
                         pack2(sb[s].x, sb[s].y), pack2(sb[s].z, sb[s].w)};
                *reinterpret_cast<uint4*>((char*)&tile[0][0] + lofs[s]) = uu;
            }
        }
    }
    __syncthreads();

    #pragma unroll 1
    for (int t = 0; t < 4; ++t) {
        // (a) issue next tile's global loads early (latency hides under MFMA)
        float4 sa[4], sb[4];
        if (t < 3) {
            const int rb = r0 + 4 * (t + 1) - 1;
            #pragma unroll
            for (int s = 0; s < 4; ++s) {
                if (s < 3 || has3) {
                    const long sr = (long)((rb + grow[s]) & (Hc - 1));
                    const char* bp = stby + (sr << 16) + gcol[s];
                    sa[s] = *reinterpret_cast<const float4*>(bp);
                    sb[s] = *reinterpret_cast<const float4*>(bp + 16);
                }
            }
        }

        // (b) compute current tile from buf[t&1]
        const char* tby = (const char*)&tile[t & 1][0];
        f32x4 acc2[4];
        #pragma unroll
        for (int pt = 0; pt < 4; ++pt) {
            acc2[pt][0] = bv.x; acc2[pt][1] = bv.y; acc2[pt][2] = bv.z; acc2[pt][3] = bv.w;
        }

        #pragma unroll
        for (int half = 0; half < 2; ++half) {
            short8 Ar[4][5];   // 4 hidden-tiles x 5 k-chunks
            #pragma unroll
            for (int tt = 0; tt < 4; ++tt) {
                #pragma unroll
                for (int i = 0; i < 5; ++i) {
                    const int ofs = abase + (64 * half + 16 * tt) * W1S + 32 * i;
                    if constexpr (USE_WS)
                        Ar[tt][i] = *reinterpret_cast<const short8*>(ws1 + ofs);
                    else
                        Ar[tt][i] = *reinterpret_cast<const short8*>(&w1f[ofs]);
                }
            }

            __builtin_amdgcn_s_setprio(1);
            #pragma unroll
            for (int pt = 0; pt < 4; ++pt) {
                short8 bf[5];
                #pragma unroll
                for (int i = 0; i < 5; ++i) {
                    if (i < 4) {
                        bf[i] = *reinterpret_cast<const short8*>(tby + baddr[i] + pt * 512);
                    } else {
                        if (g < 2) {
                            bf[i] = *reinterpret_cast<const short8*>(tby + baddr[4] + pt * 512);
                        } else if (g == 2) {
                            uint4 uu{0x3F80u, 0u, 0u, 0u};   // bf16 1.0 @ k=144 (b1)
                            bf[i] = __builtin_bit_cast(short8, uu);
                        } else {
                            uint4 uu{0u, 0u, 0u, 0u};
                            bf[i] = __builtin_bit_cast(short8, uu);
                        }
                    }
                }

                f32x4 h[4];
                #pragma unroll
                for (int tt = 0; tt < 4; ++tt) h[tt] = (f32x4){0.f, 0.f, 0.f, 0.f};
                #pragma unroll
                for (int i = 0; i < 5; ++i) {
                    #pragma unroll
                    for (int tt = 0; tt < 4; ++tt)
                        h[tt] = __builtin_amdgcn_mfma_f32_16x16x32_bf16(Ar[tt][i], bf[i], h[tt], 0, 0, 0);
                }

                // relu -> pack -> in-register transpose -> GEMM2
                #pragma unroll
                for (int pr = 0; pr < 2; ++pr) {
                    const f32x4 ha = h[2 * pr], hc = h[2 * pr + 1];
                    const unsigned Pa0 = pack2(fmaxf(ha[0], 0.f), fmaxf(ha[1], 0.f));
                    const unsigned Pa1 = pack2(fmaxf(ha[2], 0.f), fmaxf(ha[3], 0.f));
                    const unsigned Pb0 = pack2(fmaxf(hc[0], 0.f), fmaxf(hc[1], 0.f));
                    const unsigned Pb1 = pack2(fmaxf(hc[2], 0.f), fmaxf(hc[3], 0.f));
                    unsigned s0, s1, t0, t1, u0, u1, u2, u3;
                    swap32(Pa0, Pb0, s0, s1);
                    swap16(s0, s1, u0, u2);
                    swap32(Pa1, Pb1, t0, t1);
                    swap16(t0, t1, u1, u3);
                    uint4 uu{u0, u1, u2, u3};
                    acc2[pt] = __builtin_amdgcn_mfma_f32_16x16x32_bf16(
                        w2f[2 * half + pr], __builtin_bit_cast(short8, uu), acc2[pt], 0, 0, 0);
                }
            }
            __builtin_amdgcn_s_setprio(0);
        }

        // (c) store output row
        const long orow = (long)(r0 + 4 * t + wv) << 16;
        #pragma unroll
        for (int pt = 0; pt < 4; ++pt) {
            float4 o; o.x = acc2[pt][0]; o.y = acc2[pt][1]; o.z = acc2[pt][2]; o.w = acc2[pt][3];
            *reinterpret_cast<float4*>(outby + orow + ocol[pt]) = o;
        }

        // (d) write next tile into the other buffer; single barrier
        if (t < 3) {
            char* wb = (char*)&tile[(t + 1) & 1][0];
            #pragma unroll
            for (int s = 0; s < 4; ++s) {
                if (s < 3 || has3) {
                    uint4 uu{pack2(sa[s].x, sa[s].y), pack2(sa[s].z, sa[s].w),
                             pack2(sb[s].x, sb[s].y), pack2(sb[s].z, sb[s].w)};
                    *reinterpret_cast<uint4*>(wb + lofs[s]) = uu;
                }
            }
            __syncthreads();
        }
    }
}

extern "C" void kernel_launch(void* const* d_in, const int* in_sizes, int n_in,
                              void* d_out, int out_size, void* d_ws, size_t ws_size,
                              hipStream_t stream) {
    const float* state = (const float*)d_in[0];
    const float* W1c   = (const float*)d_in[1];
    const float* b1c   = (const float*)d_in[2];
    const float* W2c   = (const float*)d_in[3];
    const float* b2c   = (const float*)d_in[4];
    float* out = (float*)d_out;

    unsigned short* ws1 = (unsigned short*)d_ws;
    unsigned short* ws2 = ws1 + W1PAD;
    const size_t ws_needed = (size_t)(W1PAD + 16 * 128) * sizeof(unsigned short);

    if (ws_size >= ws_needed) {
        nca_prep<<<(W1PAD + 16 * 128 + 255) / 256, 256, 0, stream>>>(W1c, b1c, W2c, ws1, ws2);
        nca_main<true><<<1024, 256, 0, stream>>>(state, W1c, b1c, W2c, b2c, ws1, ws2, out);
    } else {
        nca_main<false><<<1024, 256, 0, stream>>>(state, W1c, b1c, W2c, b2c, ws1, ws2, out);
    }
}

// Round 11
// 68.967 us; speedup vs baseline: 1.8627x; 1.8627x over previous
//
#include <hip/hip_runtime.h>

// NCA update, fused bf16-MFMA, barrier-free decoupled-wave version.
//   out = W2 @ relu(Conv3x3(state; W1fold) + b1) + b2
// W1fold folds sobel_x/sobel_y/identity into one 16->128 3x3 conv (K=144,
// b1 at k=144; B supplies bf16 1.0 there). K padded to 160 (5 chunks of 32).
//
// Per block: 4 waves, region 16 rows x 64 cols. Each wave owns 4 CONSECUTIVE
// rows and a PRIVATE 4-slot LDS row ring (1 new input row staged per t,
// slot = row&3) -> zero __syncthreads in the main loop; waves free-run.
// W1fold is stored FRAGMENT-MAJOR (40 chunks x 1KB; lane*16 + imm offset
// ds_read_b128, conflict-free, no addressing VALU); prep emits it pre-
// permuted so global_load_lds stages it linearly.
// B-fragments loaded once per t (bf_all[4][5], 40 VGPR) -> B traffic halved.
// LDS 40.0KB (A) + 33.8KB (rings) = 73.8KB -> 2 blocks/CU; VGPR ~175 < 256
// cap at (256,2) (the only proven spill-free regalloc regime).

constexpr int Hc = 1024, Wc = 1024;
constexpr int W1FRAG = 20480;   // shorts: 40 fragment chunks x 512 shorts
constexpr int RSTRIDE = 2112;   // bytes per ring slot (66 px x 32 B)

typedef __attribute__((ext_vector_type(8))) short short8;
typedef __attribute__((ext_vector_type(4))) float f32x4;
typedef __attribute__((ext_vector_type(2))) unsigned int uint2v;

__device__ __forceinline__ unsigned short bfu(float x) {
    __bf16 b = (__bf16)x;                       // RNE
    return __builtin_bit_cast(unsigned short, b);
}
__device__ __forceinline__ unsigned pack2(float a, float b) {
    return (unsigned)bfu(a) | ((unsigned)bfu(b) << 16);
}

__device__ __forceinline__ void swap32(unsigned x, unsigned y, unsigned& o0, unsigned& o1) {
#if __has_builtin(__builtin_amdgcn_permlane32_swap)
    uint2v r = __builtin_amdgcn_permlane32_swap(x, y, false, false);
    o0 = r[0]; o1 = r[1];
#else
    unsigned xs = (unsigned)__shfl_xor((int)x, 32, 64);
    unsigned ys = (unsigned)__shfl_xor((int)y, 32, 64);
    const bool hi = (threadIdx.x & 32) != 0;
    o0 = hi ? ys : x;
    o1 = hi ? y : xs;
#endif
}
__device__ __forceinline__ void swap16(unsigned a, unsigned b, unsigned& o0, unsigned& o1) {
#if __has_builtin(__builtin_amdgcn_permlane16_swap)
    uint2v r = __builtin_amdgcn_permlane16_swap(a, b, false, false);
    o0 = r[0]; o1 = r[1];
#else
    unsigned as = (unsigned)__shfl_xor((int)a, 16, 64);
    unsigned bs = (unsigned)__shfl_xor((int)b, 16, 64);
    const bool hi = (threadIdx.x & 16) != 0;
    o0 = hi ? bs : a;
    o1 = hi ? b : as;
#endif
}

// W1fold scalar: value at (row, k) of the folded 3x3 conv matrix
__device__ __forceinline__ float w1fold_val(
    const float* __restrict__ W1c, const float* __restrict__ b1c, int row, int k)
{
    if (k < 144) {
        const int pos = k >> 4, c = k & 15;
        const int dy = pos / 3, dx = pos - dy * 3;
        float v = (float)((dx - 1) * (1 + (dy == 1))) * W1c[row * 48 + c]
                + (float)((dy - 1) * (1 + (dx == 1))) * W1c[row * 48 + 16 + c];
        if (pos == 4) v += W1c[row * 48 + 32 + c];
        return v;
    }
    return (k == 144) ? b1c[row] : 0.f;
}

// ---------------- prep: fragment-major W1fold + W2 -> bf16 in ws ----------------
// chunk j = (half*4+tt)*5 + i; within chunk lane l, elem e:
//   row = (l&15) + 16*tt + 64*half; k = 32*i + 8*(l>>4) + e
__global__ __launch_bounds__(256) void nca_prep(
    const float* __restrict__ W1c, const float* __restrict__ b1c,
    const float* __restrict__ W2c,
    unsigned short* __restrict__ ws1, unsigned short* __restrict__ ws2)
{
    const int u = blockIdx.x * 256 + threadIdx.x;
    if (u < W1FRAG) {
        const int j = u >> 9, w = u & 511;
        const int l = w >> 3, e = w & 7;
        const int half = j / 20, rem = j - half * 20;
        const int tt = rem / 5, i = rem - tt * 5;
        const int row = (l & 15) + 16 * tt + 64 * half;
        const int k = 32 * i + 8 * (l >> 4) + e;
        ws1[u] = bfu(w1fold_val(W1c, b1c, row, k));
    } else if (u < W1FRAG + 16 * 128) {
        const int w = u - W1FRAG;
        ws2[w] = bfu(W2c[w]);
    }
}

// ---------------- main ----------------
template <bool USE_WS>
__global__ __launch_bounds__(256, 2) void nca_main(
    const float* __restrict__ state,
    const float* __restrict__ W1c, const float* __restrict__ b1c,
    const float* __restrict__ W2c, const float* __restrict__ b2c,
    const unsigned short* __restrict__ ws1,   // fragment-major W1fold bf16
    const unsigned short* __restrict__ ws2,   // W2 bf16 [16][128]
    float* __restrict__ out)
{
    __shared__ short w1f[W1FRAG];             // 40960 B, fragment-major
    __shared__ short ring[4][4][RSTRIDE / 2]; // 4 waves x 4 slots x 2112 B

    const int tid  = threadIdx.x;
    const int lane = tid & 63;
    const int wv   = tid >> 6;
    const int p    = lane & 15;
    const int g    = lane >> 4;

    const int bid = (int)blockIdx.x;          // natural: XCD column striping
    const int r0 = (bid >> 4) << 4;           // 64 rowgroups x 16 rows
    const int c0 = (bid & 15) << 6;           // 16 colgroups x 64 cols
    const int x0 = r0 + 4 * wv;               // wave's first output row

    // ---- W1fold -> LDS (fragment-major; linear copy) ----
    if (USE_WS) {
        #pragma unroll
        for (int it = 0; it < 10; ++it) {
            const int chunk = it * 4 + wv;               // 40 x 1KB chunks
            const int off = chunk * 1024;
            __builtin_amdgcn_global_load_lds(
                (const __attribute__((address_space(1))) unsigned int*)
                    ((const char*)ws1 + off + lane * 16),
                (__attribute__((address_space(3))) unsigned int*)
                    ((char*)w1f + off),
                16, 0, 0);
        }
    } else {
        for (int u = tid; u < W1FRAG; u += 256) {
            const int j = u >> 9, w = u & 511;
            const int l = w >> 3, e = w & 7;
            const int half = j / 20, rem = j - half * 20;
            const int tt = rem / 5, i = rem - tt * 5;
            const int row = (l & 15) + 16 * tt + 64 * half;
            const int k = 32 * i + 8 * (l >> 4) + e;
            w1f[u] = (short)bfu(w1fold_val(W1c, b1c, row, k));
        }
    }

    // ---- W2 fragments + b2 (registers) ----
    short8 w2f[4];
    if (USE_WS) {
        const unsigned short* wsp = ws2 + p * 128 + 8 * g;
        #pragma unroll
        for (int kc = 0; kc < 4; ++kc)
            w2f[kc] = *reinterpret_cast<const short8*>(wsp + 32 * kc);
    } else {
        #pragma unroll
        for (int kc = 0; kc < 4; ++kc) {
            const float* qp = W2c + p * 128 + 32 * kc + 8 * g;
            const float4 A = *reinterpret_cast<const float4*>(qp);
            const float4 B = *reinterpret_cast<const float4*>(qp + 4);
            uint4 uu{pack2(A.x, A.y), pack2(A.z, A.w), pack2(B.x, B.y), pack2(B.z, B.w)};
            w2f[kc] = __builtin_bit_cast(short8, uu);
        }
    }
    const float4 bv = *reinterpret_cast<const float4*>(b2c + 4 * g);

    // ---- per-lane im2col constants ----
    // chunk i<4: pos = 2i + (g>>1), ch-half gb = g&1. i=4: pos 8 (loads g<2);
    // g==2 -> bf16 1.0 at k=144 (b1 fold); g==3 -> zeros.
    const int gb = g & 1;
    int dyi[5], colb[5];
    #pragma unroll
    for (int i = 0; i < 5; ++i) {
        const int pos = (i < 4) ? (2 * i + (g >> 1)) : 8;
        const int dy = pos / 3, dx = pos - 3 * dy;
        dyi[i] = dy;
        const int tc = p + dx;                                 // pt=0 pixel
        colb[i] = (tc * 32 + gb * 16) ^ ((tc & 4) << 2);       // bytes, +512/pt
    }

    // ---- row staging constants: 264 f32x4 chunks + 8 tail (lane<8) ----
    int sgc[5], swb[5];
    #pragma unroll
    for (int s = 0; s < 5; ++s) {
        const int ch = (s < 4) ? (lane + 64 * s) : (256 + lane);
        const int tc = ch >> 2, q = ch & 3;
        sgc[s] = (((c0 - 1 + tc) & (Wc - 1)) << 6) + (q << 4);  // bytes in row
        swb[s] = (tc * 32 + q * 8) ^ ((tc & 4) << 2);           // ring bytes
    }
    const bool has4 = (lane < 8);

    int ocol[4];
    #pragma unroll
    for (int pt = 0; pt < 4; ++pt) ocol[pt] = ((c0 + 16 * pt + p) << 6) + (g << 4);

    const char* stby = (const char*)state;
    char* ringw = (char*)&ring[wv][0][0];
    char* outby = (char*)out;

    // ---- prologue: stage logical rows x0-1, x0, x0+1 into private ring ----
    #pragma unroll
    for (int d = 0; d < 3; ++d) {
        const long gr = (long)((x0 - 1 + d) & (Hc - 1)) << 16;
        const int slot = ((x0 - 1 + d) & 3) * RSTRIDE;
        float4 sr5[5];
        #pragma unroll
        for (int s = 0; s < 5; ++s)
            if (s < 4 || has4)
                sr5[s] = *reinterpret_cast<const float4*>(stby + gr + sgc[s]);
        #pragma unroll
        for (int s = 0; s < 5; ++s)
            if (s < 4 || has4) {
                uint2 pk; pk.x = pack2(sr5[s].x, sr5[s].y); pk.y = pack2(sr5[s].z, sr5[s].w);
                *reinterpret_cast<uint2*>(ringw + slot + swb[s]) = pk;
            }
    }

    __syncthreads();   // w1f ready (rings are private). ONLY barrier.

    #pragma unroll 1
    for (int t = 0; t < 4; ++t) {
        const int x = x0 + t;

        // (a) issue next input row's global loads (hide under compute)
        float4 sr5[5];
        if (t < 3) {
            const long gr = (long)((x + 2) & (Hc - 1)) << 16;
            #pragma unroll
            for (int s = 0; s < 5; ++s)
                if (s < 4 || has4)
                    sr5[s] = *reinterpret_cast<const float4*>(stby + gr + sgc[s]);
        }

        // (b) load ALL B-fragments for this row once (17 ds_read_b128)
        int sb[5];
        #pragma unroll
        for (int i = 0; i < 5; ++i) sb[i] = ((x - 1 + dyi[i]) & 3) * RSTRIDE;

        short8 bfa[4][5];
        #pragma unroll
        for (int pt = 0; pt < 4; ++pt) {
            #pragma unroll
            for (int i = 0; i < 5; ++i) {
                if (i < 4) {
                    bfa[pt][i] = *reinterpret_cast<const short8*>(
                        ringw + sb[i] + colb[i] + pt * 512);
                } else {
                    if (g < 2) {
                        bfa[pt][i] = *reinterpret_cast<const short8*>(
                            ringw + sb[4] + colb[4] + pt * 512);
                    } else if (g == 2) {
                        uint4 uu{0x3F80u, 0u, 0u, 0u};   // bf16 1.0 @ k=144 (b1)
                        bfa[pt][i] = __builtin_bit_cast(short8, uu);
                    } else {
                        uint4 uu{0u, 0u, 0u, 0u};
                        bfa[pt][i] = __builtin_bit_cast(short8, uu);
                    }
                }
            }
        }

        // (c) compute
        f32x4 acc2[4];
        #pragma unroll
        for (int pt = 0; pt < 4; ++pt) {
            acc2[pt][0] = bv.x; acc2[pt][1] = bv.y; acc2[pt][2] = bv.z; acc2[pt][3] = bv.w;
        }

        #pragma unroll
        for (int half = 0; half < 2; ++half) {
            short8 Ar[4][5];   // fragment-major: lane*16 + imm offset
            #pragma unroll
            for (int tt = 0; tt < 4; ++tt) {
                #pragma unroll
                for (int i = 0; i < 5; ++i) {
                    const int j = (half * 4 + tt) * 5 + i;
                    Ar[tt][i] = *reinterpret_cast<const short8*>(
                        (char*)w1f + j * 1024 + lane * 16);
                }
            }

            __builtin_amdgcn_s_setprio(1);
            #pragma unroll
            for (int pt = 0; pt < 4; ++pt) {
                f32x4 h[4];
                #pragma unroll
                for (int tt = 0; tt < 4; ++tt) h[tt] = (f32x4){0.f, 0.f, 0.f, 0.f};
                #pragma unroll
                for (int i = 0; i < 5; ++i) {
                    #pragma unroll
                    for (int tt = 0; tt < 4; ++tt)
                        h[tt] = __builtin_amdgcn_mfma_f32_16x16x32_bf16(
                            Ar[tt][i], bfa[pt][i], h[tt], 0, 0, 0);
                }

                // relu -> pack -> in-register transpose -> GEMM2
                #pragma unroll
                for (int pr = 0; pr < 2; ++pr) {
                    const f32x4 ha = h[2 * pr], hc = h[2 * pr + 1];
                    const unsigned Pa0 = pack2(fmaxf(ha[0], 0.f), fmaxf(ha[1], 0.f));
                    const unsigned Pa1 = pack2(fmaxf(ha[2], 0.f), fmaxf(ha[3], 0.f));
                    const unsigned Pb0 = pack2(fmaxf(hc[0], 0.f), fmaxf(hc[1], 0.f));
                    const unsigned Pb1 = pack2(fmaxf(hc[2], 0.f), fmaxf(hc[3], 0.f));
                    unsigned s0, s1, t0, t1, u0, u1, u2, u3;
                    swap32(Pa0, Pb0, s0, s1);
                    swap16(s0, s1, u0, u2);
                    swap32(Pa1, Pb1, t0, t1);
                    swap16(t0, t1, u1, u3);
                    uint4 uu{u0, u1, u2, u3};
                    acc2[pt] = __builtin_amdgcn_mfma_f32_16x16x32_bf16(
                        w2f[2 * half + pr], __builtin_bit_cast(short8, uu), acc2[pt], 0, 0, 0);
                }
            }
            __builtin_amdgcn_s_setprio(0);
        }

        // (d) store output row x
        const long orow = (long)x << 16;
        #pragma unroll
        for (int pt = 0; pt < 4; ++pt) {
            float4 o; o.x = acc2[pt][0]; o.y = acc2[pt][1]; o.z = acc2[pt][2]; o.w = acc2[pt][3];
            *reinterpret_cast<float4*>(outby + orow + ocol[pt]) = o;
        }

        // (e) write staged row x+2 into ring slot (x+2)&3 (private; no barrier)
        if (t < 3) {
            const int slot = ((x + 2) & 3) * RSTRIDE;
            #pragma unroll
            for (int s = 0; s < 5; ++s)
                if (s < 4 || has4) {
                    uint2 pk; pk.x = pack2(sr5[s].x, sr5[s].y); pk.y = pack2(sr5[s].z, sr5[s].w);
                    *reinterpret_cast<uint2*>(ringw + slot + swb[s]) = pk;
                }
        }
    }
}

extern "C" void kernel_launch(void* const* d_in, const int* in_sizes, int n_in,
                              void* d_out, int out_size, void* d_ws, size_t ws_size,
                              hipStream_t stream) {
    const float* state = (const float*)d_in[0];
    const float* W1c   = (const float*)d_in[1];
    const float* b1c   = (const float*)d_in[2];
    const float* W2c   = (const float*)d_in[3];
    const float* b2c   = (const float*)d_in[4];
    float* out = (float*)d_out;

    unsigned short* ws1 = (unsigned short*)d_ws;
    unsigned short* ws2 = ws1 + W1FRAG;
    const size_t ws_needed = (size_t)(W1FRAG + 16 * 128) * sizeof(unsigned short);

    if (ws_size >= ws_needed) {
        nca_prep<<<(W1FRAG + 16 * 128 + 255) / 256, 256, 0, stream>>>(W1c, b1c, W2c, ws1, ws2);
        nca_main<true><<<1024, 256, 0, stream>>>(state, W1c, b1c, W2c, b2c, ws1, ws2, out);
    } else {
        nca_main<false><<<1024, 256, 0, stream>>>(state, W1c, b1c, W2c, b2c, ws1, ws2, out);
    }
}

// Round 12
// 66.160 us; speedup vs baseline: 1.9417x; 1.0424x over previous
//
#include <hip/hip_runtime.h>

// NCA update, fused bf16-MFMA, 4-waves/SIMD version.
//   out = W2 @ relu(Conv3x3(state; W1fold) + b1) + b2
// W1fold folds sobel_x/sobel_y/identity into one 16->128 3x3 conv (K=144,
// b1 at k=144; B supplies bf16 1.0 there). K padded to 160 (5 chunks of 32).
//
// Block: 512 threads = 8 waves, region 32 rows x 64 cols, 4 t-iters of 8
// rows (one row per wave per t). Grid 512 = exactly 2 blocks/CU, no tail.
// LDS: fragment-major W1fold 40KB + single-buffered swizzled tile (10x66)
// 21.1KB = 62.1KB -> 2 blocks/CU -> 16 waves/CU = 4/SIMD (2x all prior
// rounds; R4/R8/R11 all plateaued at 65-76us at 2 waves/SIMD).
// __launch_bounds__(512,2): VGPR cap 512/2=256; code needs ~128 (R11).
// R9's failure was (512,4) -> 64-VGPR cap -> spill; this is the fix.
// A-fragments: fragment-major ds_read_b128 at lane*16+imm (no addr VALU).
// B-fragments hoisted once per t (bfa[4][5]). Hidden transposed in-register
// (permlane32/16 swap), GEMM2 fused.

constexpr int Hc = 1024, Wc = 1024;
constexpr int W1FRAG = 20480;   // shorts: 40 fragment chunks x 512 shorts
constexpr int TCH = 1320;       // tile 16B-chunks: 10*66*2

typedef __attribute__((ext_vector_type(8))) short short8;
typedef __attribute__((ext_vector_type(4))) float f32x4;
typedef __attribute__((ext_vector_type(2))) unsigned int uint2v;

__device__ __forceinline__ unsigned short bfu(float x) {
    __bf16 b = (__bf16)x;                       // RNE
    return __builtin_bit_cast(unsigned short, b);
}
__device__ __forceinline__ unsigned pack2(float a, float b) {
    return (unsigned)bfu(a) | ((unsigned)bfu(b) << 16);
}

__device__ __forceinline__ void swap32(unsigned x, unsigned y, unsigned& o0, unsigned& o1) {
#if __has_builtin(__builtin_amdgcn_permlane32_swap)
    uint2v r = __builtin_amdgcn_permlane32_swap(x, y, false, false);
    o0 = r[0]; o1 = r[1];
#else
    unsigned xs = (unsigned)__shfl_xor((int)x, 32, 64);
    unsigned ys = (unsigned)__shfl_xor((int)y, 32, 64);
    const bool hi = (threadIdx.x & 32) != 0;
    o0 = hi ? ys : x;
    o1 = hi ? y : xs;
#endif
}
__device__ __forceinline__ void swap16(unsigned a, unsigned b, unsigned& o0, unsigned& o1) {
#if __has_builtin(__builtin_amdgcn_permlane16_swap)
    uint2v r = __builtin_amdgcn_permlane16_swap(a, b, false, false);
    o0 = r[0]; o1 = r[1];
#else
    unsigned as = (unsigned)__shfl_xor((int)a, 16, 64);
    unsigned bs = (unsigned)__shfl_xor((int)b, 16, 64);
    const bool hi = (threadIdx.x & 16) != 0;
    o0 = hi ? bs : a;
    o1 = hi ? b : as;
#endif
}

// W1fold scalar: value at (row, k) of the folded 3x3 conv matrix
__device__ __forceinline__ float w1fold_val(
    const float* __restrict__ W1c, const float* __restrict__ b1c, int row, int k)
{
    if (k < 144) {
        const int pos = k >> 4, c = k & 15;
        const int dy = pos / 3, dx = pos - dy * 3;
        float v = (float)((dx - 1) * (1 + (dy == 1))) * W1c[row * 48 + c]
                + (float)((dy - 1) * (1 + (dx == 1))) * W1c[row * 48 + 16 + c];
        if (pos == 4) v += W1c[row * 48 + 32 + c];
        return v;
    }
    return (k == 144) ? b1c[row] : 0.f;
}

// ---------------- prep: fragment-major W1fold + W2 -> bf16 in ws ----------------
// chunk j = (half*4+tt)*5 + i; within chunk lane l, elem e:
//   row = (l&15) + 16*tt + 64*half; k = 32*i + 8*(l>>4) + e
__global__ __launch_bounds__(256) void nca_prep(
    const float* __restrict__ W1c, const float* __restrict__ b1c,
    const float* __restrict__ W2c,
    unsigned short* __restrict__ ws1, unsigned short* __restrict__ ws2)
{
    const int u = blockIdx.x * 256 + threadIdx.x;
    if (u < W1FRAG) {
        const int j = u >> 9, w = u & 511;
        const int l = w >> 3, e = w & 7;
        const int half = j / 20, rem = j - half * 20;
        const int tt = rem / 5, i = rem - tt * 5;
        const int row = (l & 15) + 16 * tt + 64 * half;
        const int k = 32 * i + 8 * (l >> 4) + e;
        ws1[u] = bfu(w1fold_val(W1c, b1c, row, k));
    } else if (u < W1FRAG + 16 * 128) {
        const int w = u - W1FRAG;
        ws2[w] = bfu(W2c[w]);
    }
}

// ---------------- main ----------------
template <bool USE_WS>
__global__ __launch_bounds__(512, 2) void nca_main(
    const float* __restrict__ state,
    const float* __restrict__ W1c, const float* __restrict__ b1c,
    const float* __restrict__ W2c, const float* __restrict__ b2c,
    const unsigned short* __restrict__ ws1,   // fragment-major W1fold bf16
    const unsigned short* __restrict__ ws2,   // W2 bf16 [16][128]
    float* __restrict__ out)
{
    __shared__ short w1f[W1FRAG];             // 40960 B, fragment-major
    __shared__ short tile[10 * 66 * 16];      // 21120 B, 32B/pixel, XOR-swizzled

    const int tid  = threadIdx.x;
    const int lane = tid & 63;
    const int wv   = tid >> 6;                // 0..7
    const int p    = lane & 15;
    const int g    = lane >> 4;

    const int bid = (int)blockIdx.x;          // natural: XCD column striping
    const int r0 = (bid >> 4) << 5;           // 32 rowgroups x 32 rows
    const int c0 = (bid & 15) << 6;           // 16 colgroups x 64 cols

    // ---- W1fold -> LDS (fragment-major; linear copy, 40 x 1KB chunks) ----
    if (USE_WS) {
        #pragma unroll
        for (int it = 0; it < 5; ++it) {
            const int off = (it * 8 + wv) * 1024;
            __builtin_amdgcn_global_load_lds(
                (const __attribute__((address_space(1))) unsigned int*)
                    ((const char*)ws1 + off + lane * 16),
                (__attribute__((address_space(3))) unsigned int*)
                    ((char*)w1f + off),
                16, 0, 0);
        }
    } else {
        for (int u = tid; u < W1FRAG; u += 512) {
            const int j = u >> 9, w = u & 511;
            const int l = w >> 3, e = w & 7;
            const int half = j / 20, rem = j - half * 20;
            const int tt = rem / 5, i = rem - tt * 5;
            const int row = (l & 15) + 16 * tt + 64 * half;
            const int k = 32 * i + 8 * (l >> 4) + e;
            w1f[u] = (short)bfu(w1fold_val(W1c, b1c, row, k));
        }
    }

    // ---- staging constants: 1320 16B-chunks = 2*512 + 296 (slot 2, tid<296) ----
    // chunk j: pixel pidx=j>>1 (row tr=pidx/66, col tc=pidx%66), half hb=j&1.
    // LDS byte = j*16 ^ ((j&8)<<1)   (the (pidx&4)<<2 swizzle).
    int grow[3], gcol[3], lofs[3];
    #pragma unroll
    for (int s = 0; s < 3; ++s) {
        const int j = tid + 512 * s;
        const int jj = (j < TCH) ? j : (TCH - 1);
        const int pidx = jj >> 1, hb = jj & 1;
        const int tr = pidx / 66, tc = pidx - tr * 66;
        grow[s] = tr;
        gcol[s] = (((c0 - 1 + tc) & (Wc - 1)) << 6) + (hb << 5);   // bytes
        lofs[s] = (jj * 16) ^ ((jj & 8) << 1);                      // bytes
    }
    const bool has2 = (tid < TCH - 1024);

    // ---- W2 fragments + b2 (registers) ----
    short8 w2f[4];
    if (USE_WS) {
        const unsigned short* wsp = ws2 + p * 128 + 8 * g;
        #pragma unroll
        for (int kc = 0; kc < 4; ++kc)
            w2f[kc] = *reinterpret_cast<const short8*>(wsp + 32 * kc);
    } else {
        #pragma unroll
        for (int kc = 0; kc < 4; ++kc) {
            const float* qp = W2c + p * 128 + 32 * kc + 8 * g;
            const float4 A = *reinterpret_cast<const float4*>(qp);
            const float4 B = *reinterpret_cast<const float4*>(qp + 4);
            uint4 uu{pack2(A.x, A.y), pack2(A.z, A.w), pack2(B.x, B.y), pack2(B.z, B.w)};
            w2f[kc] = __builtin_bit_cast(short8, uu);
        }
    }
    const float4 bv = *reinterpret_cast<const float4*>(b2c + 4 * g);

    // ---- per-lane im2col B addresses (tile-local, constant across t) ----
    // chunk i<4: pos = 2i + (g>>1), ch-half gb = g&1. i=4: pos 8 (g<2);
    // g==2 -> bf16 1.0 at k=144 (b1 fold); g==3 -> zeros.
    const int gb = g & 1;
    int baddr[5];
    #pragma unroll
    for (int i = 0; i < 5; ++i) {
        const int pos = (i < 4) ? (2 * i + (g >> 1)) : 8;
        const int dy = pos / 3, dx = pos - 3 * dy;
        const int pidx = (wv + dy) * 66 + (p + dx);
        baddr[i] = (pidx * 32 + gb * 16) ^ ((pidx & 4) << 2);      // bytes
    }

    int ocol[4];
    #pragma unroll
    for (int pt = 0; pt < 4; ++pt) ocol[pt] = ((c0 + 16 * pt + p) << 6) + (g << 4);

    const char* stby = (const char*)state;
    const char* tby  = (const char*)tile;
    char* outby = (char*)out;

    // ---- prologue: stage tile for t=0 (input rows r0-1 .. r0+8) ----
    {
        float4 sa[3], sb[3];
        #pragma unroll
        for (int s = 0; s < 3; ++s) {
            if (s < 2 || has2) {
                const long sr = (long)((r0 - 1 + grow[s]) & (Hc - 1));
                const char* bp = stby + (sr << 16) + gcol[s];
                sa[s] = *reinterpret_cast<const float4*>(bp);
                sb[s] = *reinterpret_cast<const float4*>(bp + 16);
            }
        }
        #pragma unroll
        for (int s = 0; s < 3; ++s) {
            if (s < 2 || has2) {
                uint4 uu{pack2(sa[s].x, sa[s].y), pack2(sa[s].z, sa[s].w),
                         pack2(sb[s].x, sb[s].y), pack2(sb[s].z, sb[s].w)};
                *reinterpret_cast<uint4*>((char*)tile + lofs[s]) = uu;
            }
        }
    }
    __syncthreads();

    #pragma unroll 1
    for (int t = 0; t < 4; ++t) {
        // (a) load ALL B-fragments for this wave's row once (17 ds_read_b128)
        short8 bfa[4][5];
        #pragma unroll
        for (int pt = 0; pt < 4; ++pt) {
            #pragma unroll
            for (int i = 0; i < 5; ++i) {
                if (i < 4) {
                    bfa[pt][i] = *reinterpret_cast<const short8*>(tby + baddr[i] + pt * 512);
                } else {
                    if (g < 2) {
                        bfa[pt][i] = *reinterpret_cast<const short8*>(tby + baddr[4] + pt * 512);
                    } else if (g == 2) {
                        uint4 uu{0x3F80u, 0u, 0u, 0u};   // bf16 1.0 @ k=144 (b1)
                        bfa[pt][i] = __builtin_bit_cast(short8, uu);
                    } else {
                        uint4 uu{0u, 0u, 0u, 0u};
                        bfa[pt][i] = __builtin_bit_cast(short8, uu);
                    }
                }
            }
        }

        // (b) compute
        f32x4 acc2[4];
        #pragma unroll
        for (int pt = 0; pt < 4; ++pt) {
            acc2[pt][0] = bv.x; acc2[pt][1] = bv.y; acc2[pt][2] = bv.z; acc2[pt][3] = bv.w;
        }

        #pragma unroll
        for (int half = 0; half < 2; ++half) {
            short8 Ar[4][5];   // fragment-major: lane*16 + imm offset
            #pragma unroll
            for (int tt = 0; tt < 4; ++tt) {
                #pragma unroll
                for (int i = 0; i < 5; ++i) {
                    const int j = (half * 4 + tt) * 5 + i;
                    Ar[tt][i] = *reinterpret_cast<const short8*>(
                        (char*)w1f + j * 1024 + lane * 16);
                }
            }

            __builtin_amdgcn_s_setprio(1);
            #pragma unroll
            for (int pt = 0; pt < 4; ++pt) {
                f32x4 h[4];
                #pragma unroll
                for (int tt = 0; tt < 4; ++tt) h[tt] = (f32x4){0.f, 0.f, 0.f, 0.f};
                #pragma unroll
                for (int i = 0; i < 5; ++i) {
                    #pragma unroll
                    for (int tt = 0; tt < 4; ++tt)
                        h[tt] = __builtin_amdgcn_mfma_f32_16x16x32_bf16(
                            Ar[tt][i], bfa[pt][i], h[tt], 0, 0, 0);
                }

                // relu -> pack -> in-register transpose -> GEMM2
                #pragma unroll
                for (int pr = 0; pr < 2; ++pr) {
                    const f32x4 ha = h[2 * pr], hc = h[2 * pr + 1];
                    const unsigned Pa0 = pack2(fmaxf(ha[0], 0.f), fmaxf(ha[1], 0.f));
                    const unsigned Pa1 = pack2(fmaxf(ha[2], 0.f), fmaxf(ha[3], 0.f));
                    const unsigned Pb0 = pack2(fmaxf(hc[0], 0.f), fmaxf(hc[1], 0.f));
                    const unsigned Pb1 = pack2(fmaxf(hc[2], 0.f), fmaxf(hc[3], 0.f));
                    unsigned s0, s1, t0, t1, u0, u1, u2, u3;
                    swap32(Pa0, Pb0, s0, s1);
                    swap16(s0, s1, u0, u2);
                    swap32(Pa1, Pb1, t0, t1);
                    swap16(t0, t1, u1, u3);
                    uint4 uu{u0, u1, u2, u3};
                    acc2[pt] = __builtin_amdgcn_mfma_f32_16x16x32_bf16(
                        w2f[2 * half + pr], __builtin_bit_cast(short8, uu), acc2[pt], 0, 0, 0);
                }
            }
            __builtin_amdgcn_s_setprio(0);
        }

        // (c) issue next tile's global loads (live only across stores+barrier)
        float4 sa[3], sb[3];
        if (t < 3) {
            const int rb = r0 + 8 * (t + 1) - 1;
            #pragma unroll
            for (int s = 0; s < 3; ++s) {
                if (s < 2 || has2) {
                    const long sr = (long)((rb + grow[s]) & (Hc - 1));
                    const char* bp = stby + (sr << 16) + gcol[s];
                    sa[s] = *reinterpret_cast<const float4*>(bp);
                    sb[s] = *reinterpret_cast<const float4*>(bp + 16);
                }
            }
        }

        // (d) store output row
        const long orow = (long)(r0 + 8 * t + wv) << 16;
        #pragma unroll
        for (int pt = 0; pt < 4; ++pt) {
            float4 o; o.x = acc2[pt][0]; o.y = acc2[pt][1]; o.z = acc2[pt][2]; o.w = acc2[pt][3];
            *reinterpret_cast<float4*>(outby + orow + ocol[pt]) = o;
        }

        // (e) barrier (tile reads done) -> write next tile -> barrier
        if (t < 3) {
            __syncthreads();
            #pragma unroll
            for (int s = 0; s < 3; ++s) {
                if (s < 2 || has2) {
                    uint4 uu{pack2(sa[s].x, sa[s].y), pack2(sa[s].z, sa[s].w),
                             pack2(sb[s].x, sb[s].y), pack2(sb[s].z, sb[s].w)};
                    *reinterpret_cast<uint4*>((char*)tile + lofs[s]) = uu;
                }
            }
            __syncthreads();
        }
    }
}

extern "C" void kernel_launch(void* const* d_in, const int* in_sizes, int n_in,
                              void* d_out, int out_size, void* d_ws, size_t ws_size,
                              hipStream_t stream) {
    const float* state = (const float*)d_in[0];
    const float* W1c   = (const float*)d_in[1];
    const float* b1c   = (const float*)d_in[2];
    const float* W2c   = (const float*)d_in[3];
    const float* b2c   = (const float*)d_in[4];
    float* out = (float*)d_out;

    unsigned short* ws1 = (unsigned short*)d_ws;
    unsigned short* ws2 = ws1 + W1FRAG;
    const size_t ws_needed = (size_t)(W1FRAG + 16 * 128) * sizeof(unsigned short);

    if (ws_size >= ws_needed) {
        nca_prep<<<(W1FRAG + 16 * 128 + 255) / 256, 256, 0, stream>>>(W1c, b1c, W2c, ws1, ws2);
        nca_main<true><<<512, 512, 0, stream>>>(state, W1c, b1c, W2c, b2c, ws1, ws2, out);
    } else {
        nca_main<false><<<512, 512, 0, stream>>>(state, W1c, b1c, W2c, b2c, ws1, ws2, out);
    }
}